// Round 3
// baseline (97.355 us; speedup 1.0000x reference)
//
#include <hip/hip_runtime.h>

#define SEQ   3456
#define DH    32
#define FPT   216
#define NT    16
#define IMG0  20
// SCALE * log2(e): exp folded into Q pre-scale; mask/exp chain uses raw v_exp_f32.
#define SCALE2 0.25503486f

#define KPAD   40    // Ks row stride (u16): 80 B -> b128 K reads, 16B-aligned.
#define VPAD   164   // Vt row stride (u16): 328 B. MUST be >=160 (160 staged keys
                     // per dim row -- VPAD=152 in r2 truncated rows: OOB + race).
                     // b64 PV read bank-pairs = (9*col+quad) mod 16: uniform,
                     // 4 lane-halves/pair = structural min, no excess conflict.
                     // LDS total = 2*160*40*2 + 32*164*2 = 36096 B -> 4 WGs/CU.

typedef __attribute__((ext_vector_type(8))) short bf16x8;
typedef __attribute__((ext_vector_type(4))) short bf16x4;
typedef __attribute__((ext_vector_type(4))) float f32x4;

#define MFMA16(a,b,c) __builtin_amdgcn_mfma_f32_16x16x32_bf16(a,b,c,0,0,0)

__device__ __forceinline__ unsigned short bfh(float f) {      // fp32->bf16 RTNE
    unsigned u = __float_as_uint(f);
    u += 0x7FFFu + ((u >> 16) & 1u);
    return (unsigned short)(u >> 16);
}
__device__ __forceinline__ float bff(unsigned short h) {
    return __uint_as_float((unsigned)h << 16);
}
__device__ __forceinline__ void split8(const float* f, bf16x8& hi, bf16x8& lo) {
    #pragma unroll
    for (int j = 0; j < 8; ++j) {
        unsigned short h = bfh(f[j]);
        hi[j] = (short)h;
        lo[j] = (short)bfh(f[j] - bff(h));
    }
}
__device__ __forceinline__ bf16x8 ld2x64(const unsigned short* p0, const unsigned short* p1) {
    const bf16x4 a = *(const bf16x4*)p0;
    const bf16x4 b = *(const bf16x4*)p1;
    bf16x8 r;
    #pragma unroll
    for (int j = 0; j < 4; ++j) { r[j] = a[j]; r[4 + j] = b[j]; }
    return r;
}

// Swapped-operand scheme (P stays in registers; no LDS roundtrip):
//  QK^T: S^T = MFMA(A=K, B=Q). A/B frags both [lane&15][quad*8+j], so K reads
//  and Q registers are IDENTICAL to the unswapped kernel; only arg order flips.
//  D = S^T[key=16h+4*quad+r][q=col] -> lane-local P^T after mask/exp.
//  PV:   k-slot map key(quad,j) = 16*(j>>2) + 4*quad + (j&3). B-frag = own
//  packed bf16 P values (lane-local!); A-frag = V^T via 2x b64 (+0,+32B).
//  O^T accumulates D[d=16h2+4*quad+r][q=col] -> dwordx4 epilogue stores.
//  l: one MFMA(ones, P) -> every D-row holds l[q]; no shuffle broadcast.
//  (k-permutation-safe: A and B use the same slot->key map on both MFMAs.)
// Accuracy: QK 3-term bf16 compensation; P/V hi-only (rounding cancels in the
// softmax ratio: l is summed via MFMA from the SAME rounded P as PV).
__global__ __launch_bounds__(256, 4)
void eye_attn_mfma3(const float* __restrict__ q, const float* __restrict__ k,
                    const float* __restrict__ v, float* __restrict__ out) {
    __shared__ __align__(16) unsigned short KsHi[160 * KPAD];   // 12.5 KB
    __shared__ __align__(16) unsigned short KsLo[160 * KPAD];   // 12.5 KB
    __shared__ __align__(16) unsigned short VtHi[DH * VPAD];    // 10.25 KB

    const int t = blockIdx.x, bh = blockIdx.y, half = blockIdx.z;
    const int tid = threadIdx.x;
    const size_t base = (size_t)bh * SEQ * DH;
    const int dmax = (t < 7) ? t : 7;
    const int nkeys = IMG0 * (dmax + 1);     // staged small keys (g = d*20+jj)

    // ---- stage small K (hi/lo rows) and V^T (hi only), zero-padded ----
    for (int i = tid; i < 160 * 8; i += 256) {
        const int g = i >> 3, c = i & 7;
        float4 kk = make_float4(0.f,0.f,0.f,0.f), vv = make_float4(0.f,0.f,0.f,0.f);
        if (g < nkeys) {
            const int d = g / IMG0, jj = g - d * IMG0;
            const size_t row = base + (size_t)((t - d) * FPT + jj) * DH + c * 4;
            kk = *(const float4*)(k + row);
            vv = *(const float4*)(v + row);
        }
        const float kf[4] = {kk.x, kk.y, kk.z, kk.w};
        const float vf[4] = {vv.x, vv.y, vv.z, vv.w};
        ushort4 khi, klo;
        unsigned short* ah = (unsigned short*)&khi;
        unsigned short* al = (unsigned short*)&klo;
        #pragma unroll
        for (int e = 0; e < 4; ++e) {
            const unsigned short h = bfh(kf[e]);
            ah[e] = h;
            al[e] = bfh(kf[e] - bff(h));
        }
        *(ushort4*)(KsHi + g * KPAD + c * 4) = khi;
        *(ushort4*)(KsLo + g * KPAD + c * 4) = klo;
        #pragma unroll
        for (int e = 0; e < 4; ++e)
            VtHi[(c * 4 + e) * VPAD + g] = bfh(vf[e]);
    }
    __syncthreads();   // only barrier

    const int wv = tid >> 6, lane = tid & 63;
    const int col = lane & 15, quad = lane >> 4;

    // 14 M-tiles over 2 WGs x 4 waves; img work (tiles 0,1) goes to the
    // 1-tile waves of half 0: w0/w1 do 5+7=12 kt-units, others 10.
    int mt[2]; int mcnt; bool do_img = false;
    if (half == 0) {
        if (wv == 0)      { mt[0] = 0; mcnt = 1; do_img = true; }
        else if (wv == 1) { mt[0] = 1; mcnt = 1; do_img = true; }
        else if (wv == 2) { mt[0] = 2; mt[1] = 3; mcnt = 2; }
        else              { mt[0] = 4; mt[1] = 5; mcnt = 2; }
    } else {
        mt[0] = 6 + 2 * wv; mt[1] = 7 + 2 * wv; mcnt = 2;
    }

    bf16x8 ones8;   // A = all-ones: D[row][q] = l[q] for every row
    #pragma unroll
    for (int j = 0; j < 8; ++j) ones8[j] = (short)0x3F80;

    const int nkt = (nkeys + 31) >> 5;
    const int gq = quad * 4;                 // per-lane key-local row base

    for (int mi = 0; mi < mcnt; ++mi) {
        const int mb = mt[mi] * 16;
        const int qm = mb + col;             // this lane's query column
        const bool qok = qm < FPT;
        const bool qj  = (qm >= 4) && (qm < IMG0);
        bf16x8 qhi, qlo;
        {
            const int qc = min(qm, FPT - 1);   // clamp; masked via vis
            const float* qp = q + base + (size_t)(t * FPT + qc) * DH + quad * 8;
            float qf[8];
            const float4 a0 = *(const float4*)qp;
            const float4 a1 = *(const float4*)(qp + 4);
            qf[0]=a0.x*SCALE2; qf[1]=a0.y*SCALE2; qf[2]=a0.z*SCALE2; qf[3]=a0.w*SCALE2;
            qf[4]=a1.x*SCALE2; qf[5]=a1.y*SCALE2; qf[6]=a1.z*SCALE2; qf[7]=a1.w*SCALE2;
            split8(qf, qhi, qlo);
        }
        f32x4 oacc0 = {0.f,0.f,0.f,0.f}, oacc1 = {0.f,0.f,0.f,0.f};
        f32x4 lacc = {0.f,0.f,0.f,0.f};

        // ---- small keys: S^T -> mask/exp2 -> in-reg P -> PV + l ----
        for (int kt = 0; kt < nkt; ++kt) {
            f32x4 s[2];
            #pragma unroll
            for (int h = 0; h < 2; ++h) {
                const int key = kt * 32 + h * 16 + col;       // A-frag row
                const bf16x8 khi = *(const bf16x8*)(KsHi + key * KPAD + quad * 8);
                const bf16x8 klo = *(const bf16x8*)(KsLo + key * KPAD + quad * 8);
                f32x4 acc = {0.f,0.f,0.f,0.f};
                acc = MFMA16(khi, qhi, acc);
                acc = MFMA16(khi, qlo, acc);
                acc = MFMA16(klo, qhi, acc);
                s[h] = acc;
            }
            bf16x8 pb;    // B[k=quad*8+j][q] = P^T[key(quad,j)][qm], lane-local
            #pragma unroll
            for (int h = 0; h < 2; ++h) {
                #pragma unroll
                for (int r = 0; r < 4; ++r) {
                    const int g = kt * 32 + h * 16 + gq + r;  // key index
                    const int d = g / IMG0, jj = g - d * IMG0;
                    const bool vis = (g < nkeys) && qok &&
                                     ((d == 0) || ((jj != 4) && !(qj && jj >= 4)));
                    const float e = vis ? __builtin_amdgcn_exp2f(s[h][r]) : 0.f;
                    pb[h * 4 + r] = (short)bfh(e);
                }
            }
            lacc = MFMA16(ones8, pb, lacc);
            #pragma unroll
            for (int h2 = 0; h2 < 2; ++h2) {
                const unsigned short* vp = VtHi + (h2 * 16 + col) * VPAD + kt * 32 + quad * 4;
                const bf16x8 va = ld2x64(vp, vp + 16);        // keys (quad,j<4), (quad,j>=4)
                f32x4& oa = h2 ? oacc1 : oacc0;
                oa = MFMA16(va, pb, oa);
            }
        }

        // ---- same-t img keys (20..215): only queries < 20 (M-tiles 0,1) ----
        if (mi == 0 && do_img) {
            for (int kt2 = 0; kt2 < 7; ++kt2) {
                f32x4 s[2];
                #pragma unroll
                for (int h = 0; h < 2; ++h) {
                    const int keyc = min(IMG0 + kt2 * 32 + h * 16 + col, FPT - 1);
                    const float* kp = k + base + (size_t)(t * FPT + keyc) * DH + quad * 8;
                    float kf[8];
                    const float4 a0 = *(const float4*)kp;
                    const float4 a1 = *(const float4*)(kp + 4);
                    kf[0]=a0.x; kf[1]=a0.y; kf[2]=a0.z; kf[3]=a0.w;
                    kf[4]=a1.x; kf[5]=a1.y; kf[6]=a1.z; kf[7]=a1.w;
                    bf16x8 khi, klo;
                    split8(kf, khi, klo);
                    f32x4 acc = {0.f,0.f,0.f,0.f};
                    acc = MFMA16(khi, qhi, acc);
                    acc = MFMA16(khi, qlo, acc);
                    acc = MFMA16(klo, qhi, acc);
                    s[h] = acc;
                }
                bf16x8 pb;
                #pragma unroll
                for (int h = 0; h < 2; ++h) {
                    #pragma unroll
                    for (int r = 0; r < 4; ++r) {
                        const int key = IMG0 + kt2 * 32 + h * 16 + gq + r;
                        const bool vis = (key < FPT) && (qm < IMG0);
                        const float e = vis ? __builtin_amdgcn_exp2f(s[h][r]) : 0.f;
                        pb[h * 4 + r] = (short)bfh(e);
                    }
                }
                lacc = MFMA16(ones8, pb, lacc);
                #pragma unroll
                for (int h2 = 0; h2 < 2; ++h2) {
                    float vf[8];
                    #pragma unroll
                    for (int j = 0; j < 8; ++j) {
                        const int ky = min(IMG0 + kt2 * 32 + 16 * (j >> 2) + gq + (j & 3), FPT - 1);
                        vf[j] = v[base + (size_t)(t * FPT + ky) * DH + h2 * 16 + col];
                    }
                    bf16x8 va;
                    #pragma unroll
                    for (int j = 0; j < 8; ++j) va[j] = (short)bfh(vf[j]);
                    f32x4& oa = h2 ? oacc1 : oacc0;
                    oa = MFMA16(va, pb, oa);
                }
            }
        }

        // ---- epilogue: l is every row of lacc; 2x dwordx4 per lane ----
        if (qok) {
            const float inv = 1.f / lacc[0];
            float* op = out + base + (size_t)(t * FPT + qm) * DH;
            float4 o0, o1;
            o0.x = oacc0[0]*inv; o0.y = oacc0[1]*inv; o0.z = oacc0[2]*inv; o0.w = oacc0[3]*inv;
            o1.x = oacc1[0]*inv; o1.y = oacc1[1]*inv; o1.z = oacc1[2]*inv; o1.w = oacc1[3]*inv;
            *(float4*)(op + quad * 4)      = o0;
            *(float4*)(op + 16 + quad * 4) = o1;
        }
    }
}

extern "C" void kernel_launch(void* const* d_in, const int* in_sizes, int n_in,
                              void* d_out, int out_size, void* d_ws, size_t ws_size,
                              hipStream_t stream) {
    const float* q = (const float*)d_in[0];
    const float* k = (const float*)d_in[1];
    const float* v = (const float*)d_in[2];
    float* out = (float*)d_out;
    const int BH = in_sizes[0] / (SEQ * DH);   // 24
    dim3 grid(NT, BH, 2);                      // M-split: 768 WGs
    eye_attn_mfma3<<<grid, 256, 0, stream>>>(q, k, v, out);
}